// Round 1
// baseline (354.242 us; speedup 1.0000x reference)
//
#include <hip/hip_runtime.h>

typedef unsigned int u32;
typedef unsigned short u16;
typedef __attribute__((ext_vector_type(8))) short bf16x8;
typedef __attribute__((ext_vector_type(4))) float f32x4;

// ---------------- helpers ----------------
__device__ __forceinline__ u32 f2bf(float f) {
  u32 x = __float_as_uint(f);
  return (x + 0x7fffu + ((x >> 16) & 1u)) >> 16;   // RNE to bf16 bits
}

// ---------------- weight prep: bf16, transposed, pre-swizzled ----------------
// G layout (u16): G[c*128 + (k ^ ((c&7)<<3))] = bf16(W[k][c]), c in [0,256):
//   c<128 -> Wl col c ; c>=128 -> Wr col (c-128).
// Linear copy of G into LDS yields swizzled col-major weights Bt[c][k].
__global__ void prep_weights_kernel(const float* __restrict__ Wl,
                                    const float* __restrict__ Wr,
                                    u16* __restrict__ G) {
  int id = blockIdx.x * 256 + threadIdx.x;
  if (id >= 256 * 128) return;
  int c = id >> 7;
  int k = id & 127;
  const float* W = (c < 128) ? Wl : Wr;
  float v = W[k * 128 + (c & 127)];
  G[c * 128 + (k ^ ((c & 7) << 3))] = (u16)f2bf(v);
}

// ---------------- CSR build ----------------
__global__ void hist_kernel(const int* __restrict__ dst, int* __restrict__ cnt, int E) {
  int e = blockIdx.x * blockDim.x + threadIdx.x;
  if (e < E) atomicAdd(&cnt[dst[e]], 1);
}

__global__ void scan_kernel(const int* __restrict__ cnt, int* __restrict__ row_ptr,
                            int* __restrict__ fill_pos, float* __restrict__ inv_cnt, int n) {
  const int T = 1024;
  __shared__ int sums[T];
  int t = threadIdx.x;
  int chunk = (n + T - 1) / T;
  int lo = t * chunk, hi = min(lo + chunk, n);
  int s = 0;
  for (int i = lo; i < hi; ++i) s += cnt[i];
  sums[t] = s;
  __syncthreads();
  for (int off = 1; off < T; off <<= 1) {
    int add = (t >= off) ? sums[t - off] : 0;
    __syncthreads();
    sums[t] += add;
    __syncthreads();
  }
  int run = (t == 0) ? 0 : sums[t - 1];
  for (int i = lo; i < hi; ++i) {
    int c = cnt[i];
    row_ptr[i] = run;
    fill_pos[i] = run;
    inv_cnt[i] = 1.0f / (float)max(c, 1);
    run += c;
  }
  if (t == T - 1) row_ptr[n] = sums[T - 1];
}

__global__ void fill_kernel(const int* __restrict__ src, const int* __restrict__ dst,
                            int* __restrict__ fill_pos, int* __restrict__ col, int E) {
  int e = blockIdx.x * blockDim.x + threadIdx.x;
  if (e < E) {
    int d = dst[e];
    int pos = atomicAdd(&fill_pos[d], 1);
    col[pos] = src[e];
  }
}

// ---------------- fused dual GEMM: yl = in@Wl ; yr = in@Wr + b ----------------
// 64 rows x 256 cols per block (cols 0-127 -> yl, 128-255 -> yr). bf16 MFMA.
// LDS: As swizzled [64][128] bf16 (16KB) + Bt swizzled [256][128] bf16 (64KB) = 80KB
__global__ __launch_bounds__(256, 2) void gemm_dual_kernel(
    const float* __restrict__ in, const u16* __restrict__ G,
    const float* __restrict__ bias, float* __restrict__ yl, float* __restrict__ yr, int n) {
  __shared__ uint4 lds4[5120];                 // 80 KB
  char* As = (char*)lds4;                      // bytes [0, 16384)
  char* Bt = (char*)lds4 + 16384;              // bytes [16384, 81920)
  const int t = threadIdx.x;
  const int lane = t & 63;
  const int wave = t >> 6;
  const int row0 = blockIdx.x * 64;

  // stage B: linear 64 KB copy (G is pre-swizzled)
  {
    const uint4* gb = (const uint4*)G;
    uint4* lb = lds4 + 1024;
#pragma unroll
    for (int i = 0; i < 16; ++i) lb[i * 256 + t] = gb[i * 256 + t];
  }
  // stage A: 64 rows x 128 fp32 -> bf16, swizzled 16B granules
#pragma unroll
  for (int i = 0; i < 4; ++i) {
    int g = t + i * 256;                       // granule id 0..1023
    int r = g >> 4;
    int gc = g & 15;
    int row = row0 + r;
    float4 v0 = {0.f, 0.f, 0.f, 0.f}, v1 = {0.f, 0.f, 0.f, 0.f};
    if (row < n) {
      const float4* p = (const float4*)(in + (size_t)row * 128 + gc * 8);
      v0 = p[0];
      v1 = p[1];
    }
    uint4 pk;
    pk.x = f2bf(v0.x) | (f2bf(v0.y) << 16);
    pk.y = f2bf(v0.z) | (f2bf(v0.w) << 16);
    pk.z = f2bf(v1.x) | (f2bf(v1.y) << 16);
    pk.w = f2bf(v1.z) | (f2bf(v1.w) << 16);
    *(uint4*)(As + r * 256 + ((gc * 16) ^ ((r & 7) << 4))) = pk;
  }
  __syncthreads();

  const int wr = wave >> 1;                    // 0..1 : rows wr*32
  const int wc = wave & 1;                     // 0..1 : cols wc*128
  const int lhi = lane >> 4;                   // k-group
  const int llo = lane & 15;

  f32x4 acc[2][8];
#pragma unroll
  for (int fr = 0; fr < 2; ++fr)
#pragma unroll
    for (int fc = 0; fc < 8; ++fc) acc[fr][fc] = {0.f, 0.f, 0.f, 0.f};

#pragma unroll
  for (int ks = 0; ks < 4; ++ks) {
    const int kbyte = ks * 64 + lhi * 16;      // byte offset of this lane's 8 bf16
    bf16x8 a[2], b[8];
#pragma unroll
    for (int fr = 0; fr < 2; ++fr) {
      int r = wr * 32 + fr * 16 + llo;
      a[fr] = *(const bf16x8*)(As + r * 256 + (kbyte ^ ((r & 7) << 4)));
    }
#pragma unroll
    for (int fc = 0; fc < 8; ++fc) {
      int c = wc * 128 + fc * 16 + llo;
      b[fc] = *(const bf16x8*)(Bt + c * 256 + (kbyte ^ ((c & 7) << 4)));
    }
#pragma unroll
    for (int fr = 0; fr < 2; ++fr)
#pragma unroll
      for (int fc = 0; fc < 8; ++fc)
        acc[fr][fc] = __builtin_amdgcn_mfma_f32_16x16x32_bf16(a[fr], b[fc], acc[fr][fc], 0, 0, 0);
  }

  // epilogue: C layout col=lane&15, row=(lane>>4)*4+i  (m89-verified)
#pragma unroll
  for (int fc = 0; fc < 8; ++fc) {
    int c = wc * 128 + fc * 16 + llo;
    int isR = (c >= 128);
    int cc = c & 127;
    float bv = isR ? bias[cc] : 0.0f;
    float* outp = isR ? yr : yl;
#pragma unroll
    for (int fr = 0; fr < 2; ++fr) {
#pragma unroll
      for (int i = 0; i < 4; ++i) {
        int row = row0 + wr * 32 + fr * 16 + lhi * 4 + i;
        if (row < n) outp[(size_t)row * 128 + cc] = acc[fr][fc][i] + bv;
      }
    }
  }
}

// ---------------- aggregation: out = relu?(inv_cnt * sum_nb(yl) + yr) ----------------
template <int RELU>
__global__ __launch_bounds__(256) void agg_kernel(
    const float* __restrict__ yl, const float* __restrict__ yr,
    const int* __restrict__ row_ptr, const int* __restrict__ colv,
    const float* __restrict__ inv_cnt, float* __restrict__ out, int n) {
  int node = blockIdx.x * 4 + (threadIdx.x >> 6);
  if (node >= n) return;
  int lane = threadIdx.x & 63;
  int beg = row_ptr[node], end = row_ptr[node + 1];
  float ax = 0.f, ay = 0.f;
  int e = beg;
  for (; e + 4 <= end; e += 4) {
    int s0 = colv[e], s1 = colv[e + 1], s2 = colv[e + 2], s3 = colv[e + 3];
    float2 v0 = *(const float2*)(yl + (size_t)s0 * 128 + lane * 2);
    float2 v1 = *(const float2*)(yl + (size_t)s1 * 128 + lane * 2);
    float2 v2 = *(const float2*)(yl + (size_t)s2 * 128 + lane * 2);
    float2 v3 = *(const float2*)(yl + (size_t)s3 * 128 + lane * 2);
    ax += (v0.x + v1.x) + (v2.x + v3.x);
    ay += (v0.y + v1.y) + (v2.y + v3.y);
  }
  for (; e < end; ++e) {
    float2 v = *(const float2*)(yl + (size_t)colv[e] * 128 + lane * 2);
    ax += v.x;
    ay += v.y;
  }
  float s = inv_cnt[node];
  float2 r = *(const float2*)(yr + (size_t)node * 128 + lane * 2);
  float ox = ax * s + r.x;
  float oy = ay * s + r.y;
  if (RELU) {
    ox = fmaxf(ox, 0.f);
    oy = fmaxf(oy, 0.f);
  }
  float2 o = {ox, oy};
  *(float2*)(out + (size_t)node * 128 + lane * 2) = o;
}

// ---------------- launch ----------------
extern "C" void kernel_launch(void* const* d_in, const int* in_sizes, int n_in,
                              void* d_out, int out_size, void* d_ws, size_t ws_size,
                              hipStream_t stream) {
  const float* x = (const float*)d_in[0];
  const int* ei = (const int*)d_in[1];
  const float* Wl1 = (const float*)d_in[2];
  const float* Wr1 = (const float*)d_in[3];
  const float* b1 = (const float*)d_in[4];
  const float* Wl2 = (const float*)d_in[5];
  const float* Wr2 = (const float*)d_in[6];
  const float* b2 = (const float*)d_in[7];

  const int N = in_sizes[0] / 128;
  const int E = in_sizes[1] / 2;
  const int* srcv = ei;
  const int* dstv = ei + E;

  char* ws = (char*)d_ws;
  float* bufA = (float*)ws;   ws += (size_t)N * 128 * 4;   // xl / yl
  float* bufB = (float*)ws;   ws += (size_t)N * 128 * 4;   // xr / yr
  u16* G1 = (u16*)ws;         ws += 256 * 128 * 2;
  u16* G2 = (u16*)ws;         ws += 256 * 128 * 2;
  int* colv = (int*)ws;       ws += (size_t)E * 4;
  int* row_ptr = (int*)ws;    ws += ((size_t)N + 64) * 4;
  int* fill_pos = (int*)ws;   ws += (size_t)N * 4;
  int* cnt = (int*)ws;        ws += (size_t)N * 4;
  float* invc = (float*)ws;   ws += (size_t)N * 4;
  float* h = (float*)d_out;   // layer-1 output lives in d_out, overwritten by layer 2

  hipMemsetAsync(cnt, 0, (size_t)N * 4, stream);
  prep_weights_kernel<<<128, 256, 0, stream>>>(Wl1, Wr1, G1);
  prep_weights_kernel<<<128, 256, 0, stream>>>(Wl2, Wr2, G2);
  hist_kernel<<<(E + 255) / 256, 256, 0, stream>>>(dstv, cnt, E);
  scan_kernel<<<1, 1024, 0, stream>>>(cnt, row_ptr, fill_pos, invc, N);
  fill_kernel<<<(E + 255) / 256, 256, 0, stream>>>(srcv, dstv, fill_pos, colv, E);

  int gblocks = (N + 63) / 64;
  gemm_dual_kernel<<<gblocks, 256, 0, stream>>>(x, G1, b1, bufA, bufB, N);
  agg_kernel<1><<<(N + 3) / 4, 256, 0, stream>>>(bufA, bufB, row_ptr, colv, invc, h, N);
  gemm_dual_kernel<<<gblocks, 256, 0, stream>>>(h, G2, b2, bufA, bufB, N);
  agg_kernel<0><<<(N + 3) / 4, 256, 0, stream>>>(bufA, bufB, row_ptr, colv, invc, (float*)d_out, N);
}

// Round 2
// 234.556 us; speedup vs baseline: 1.5103x; 1.5103x over previous
//
#include <hip/hip_runtime.h>

typedef unsigned int u32;
typedef unsigned short u16;
typedef __attribute__((ext_vector_type(8))) short bf16x8;
typedef __attribute__((ext_vector_type(4))) float f32x4;

// ---------------- helpers ----------------
__device__ __forceinline__ u32 f2bf(float f) {
  u32 x = __float_as_uint(f);
  return (x + 0x7fffu + ((x >> 16) & 1u)) >> 16;   // RNE to bf16 bits
}

// ---------------- weight prep: bf16, transposed, pre-swizzled ----------------
// G layout (u16): G[c*128 + (k ^ ((c&7)<<3))] = bf16(W[k][c]), c in [0,256):
//   c<128 -> Wl col c ; c>=128 -> Wr col (c-128).
// Linear copy of G into LDS yields swizzled col-major weights Bt[c][k].
__global__ void prep_weights_kernel(const float* __restrict__ Wl,
                                    const float* __restrict__ Wr,
                                    u16* __restrict__ G) {
  int id = blockIdx.x * 256 + threadIdx.x;
  if (id >= 256 * 128) return;
  int c = id >> 7;
  int k = id & 127;
  const float* W = (c < 128) ? Wl : Wr;
  float v = W[k * 128 + (c & 127)];
  G[c * 128 + (k ^ ((c & 7) << 3))] = (u16)f2bf(v);
}

// ---------------- CSR build ----------------
__global__ void hist_kernel(const int* __restrict__ dst, int* __restrict__ cnt, int E) {
  int e = blockIdx.x * blockDim.x + threadIdx.x;
  if (e < E) atomicAdd(&cnt[dst[e]], 1);
}

// ---- multi-block scan: 2048 elems/block (256 thr x 8) ----
#define SCAN_CHUNK 2048

__global__ __launch_bounds__(256) void scan_sums(const int* __restrict__ cnt,
                                                 int* __restrict__ bsum, int n) {
  __shared__ int red[256];
  int t = threadIdx.x;
  int base = blockIdx.x * SCAN_CHUNK + t * 8;
  int s = 0;
#pragma unroll
  for (int i = 0; i < 8; ++i) {
    int idx = base + i;
    if (idx < n) s += cnt[idx];
  }
  red[t] = s;
  __syncthreads();
  for (int off = 128; off > 0; off >>= 1) {
    if (t < off) red[t] += red[t + off];
    __syncthreads();
  }
  if (t == 0) bsum[blockIdx.x] = red[0];
}

__global__ void scan_bsum(int* __restrict__ bsum, int nb, int* __restrict__ row_ptr_n) {
  if (threadIdx.x == 0) {
    int run = 0;
    for (int i = 0; i < nb; ++i) {
      int c = bsum[i];
      bsum[i] = run;
      run += c;
    }
    *row_ptr_n = run;   // row_ptr[n] = E
  }
}

__global__ __launch_bounds__(256) void scan_apply(
    const int* __restrict__ cnt, const int* __restrict__ bsum,
    int* __restrict__ row_ptr, int* __restrict__ fill_pos,
    float* __restrict__ inv_cnt, int n) {
  __shared__ int sc[256];
  int t = threadIdx.x;
  int base = blockIdx.x * SCAN_CHUNK + t * 8;
  int v[8];
  int s = 0;
#pragma unroll
  for (int i = 0; i < 8; ++i) {
    int idx = base + i;
    v[i] = (idx < n) ? cnt[idx] : 0;
    s += v[i];
  }
  sc[t] = s;
  __syncthreads();
  // Hillis-Steele inclusive scan over per-thread sums
  for (int off = 1; off < 256; off <<= 1) {
    int add = (t >= off) ? sc[t - off] : 0;
    __syncthreads();
    sc[t] += add;
    __syncthreads();
  }
  int run = bsum[blockIdx.x] + ((t > 0) ? sc[t - 1] : 0);
#pragma unroll
  for (int i = 0; i < 8; ++i) {
    int idx = base + i;
    if (idx < n) {
      row_ptr[idx] = run;
      fill_pos[idx] = run;
      inv_cnt[idx] = 1.0f / (float)max(v[i], 1);
      run += v[i];
    }
  }
}

__global__ void fill_kernel(const int* __restrict__ src, const int* __restrict__ dst,
                            int* __restrict__ fill_pos, int* __restrict__ col, int E) {
  int e = blockIdx.x * blockDim.x + threadIdx.x;
  if (e < E) {
    int d = dst[e];
    int pos = atomicAdd(&fill_pos[d], 1);
    col[pos] = src[e];
  }
}

// ---------------- fused dual GEMM: yl = in@Wl ; yr = in@Wr + b ----------------
// 64 rows x 256 cols per block (cols 0-127 -> yl, 128-255 -> yr). bf16 MFMA.
// LDS: As swizzled [64][128] bf16 (16KB) + Bt swizzled [256][128] bf16 (64KB) = 80KB
__global__ __launch_bounds__(256, 2) void gemm_dual_kernel(
    const float* __restrict__ in, const u16* __restrict__ G,
    const float* __restrict__ bias, float* __restrict__ yl, float* __restrict__ yr, int n) {
  __shared__ uint4 lds4[5120];                 // 80 KB
  char* As = (char*)lds4;                      // bytes [0, 16384)
  char* Bt = (char*)lds4 + 16384;              // bytes [16384, 81920)
  const int t = threadIdx.x;
  const int lane = t & 63;
  const int wave = t >> 6;
  const int row0 = blockIdx.x * 64;

  // stage B: linear 64 KB copy (G is pre-swizzled)
  {
    const uint4* gb = (const uint4*)G;
    uint4* lb = lds4 + 1024;
#pragma unroll
    for (int i = 0; i < 16; ++i) lb[i * 256 + t] = gb[i * 256 + t];
  }
  // stage A: 64 rows x 128 fp32 -> bf16, swizzled 16B granules
#pragma unroll
  for (int i = 0; i < 4; ++i) {
    int g = t + i * 256;                       // granule id 0..1023
    int r = g >> 4;
    int gc = g & 15;
    int row = row0 + r;
    float4 v0 = {0.f, 0.f, 0.f, 0.f}, v1 = {0.f, 0.f, 0.f, 0.f};
    if (row < n) {
      const float4* p = (const float4*)(in + (size_t)row * 128 + gc * 8);
      v0 = p[0];
      v1 = p[1];
    }
    uint4 pk;
    pk.x = f2bf(v0.x) | (f2bf(v0.y) << 16);
    pk.y = f2bf(v0.z) | (f2bf(v0.w) << 16);
    pk.z = f2bf(v1.x) | (f2bf(v1.y) << 16);
    pk.w = f2bf(v1.z) | (f2bf(v1.w) << 16);
    *(uint4*)(As + r * 256 + ((gc * 16) ^ ((r & 7) << 4))) = pk;
  }
  __syncthreads();

  const int wr = wave >> 1;                    // 0..1 : rows wr*32
  const int wc = wave & 1;                     // 0..1 : cols wc*128
  const int lhi = lane >> 4;                   // k-group
  const int llo = lane & 15;

  f32x4 acc[2][8];
#pragma unroll
  for (int fr = 0; fr < 2; ++fr)
#pragma unroll
    for (int fc = 0; fc < 8; ++fc) acc[fr][fc] = {0.f, 0.f, 0.f, 0.f};

#pragma unroll
  for (int ks = 0; ks < 4; ++ks) {
    const int kbyte = ks * 64 + lhi * 16;      // byte offset of this lane's 8 bf16
    bf16x8 a[2], b[8];
#pragma unroll
    for (int fr = 0; fr < 2; ++fr) {
      int r = wr * 32 + fr * 16 + llo;
      a[fr] = *(const bf16x8*)(As + r * 256 + (kbyte ^ ((r & 7) << 4)));
    }
#pragma unroll
    for (int fc = 0; fc < 8; ++fc) {
      int c = wc * 128 + fc * 16 + llo;
      b[fc] = *(const bf16x8*)(Bt + c * 256 + (kbyte ^ ((c & 7) << 4)));
    }
#pragma unroll
    for (int fr = 0; fr < 2; ++fr)
#pragma unroll
      for (int fc = 0; fc < 8; ++fc)
        acc[fr][fc] = __builtin_amdgcn_mfma_f32_16x16x32_bf16(a[fr], b[fc], acc[fr][fc], 0, 0, 0);
  }

  // epilogue: C layout col=lane&15, row=(lane>>4)*4+i  (m89-verified)
#pragma unroll
  for (int fc = 0; fc < 8; ++fc) {
    int c = wc * 128 + fc * 16 + llo;
    int isR = (c >= 128);
    int cc = c & 127;
    float bv = isR ? bias[cc] : 0.0f;
    float* outp = isR ? yr : yl;
#pragma unroll
    for (int fr = 0; fr < 2; ++fr) {
#pragma unroll
      for (int i = 0; i < 4; ++i) {
        int row = row0 + wr * 32 + fr * 16 + lhi * 4 + i;
        if (row < n) outp[(size_t)row * 128 + cc] = acc[fr][fc][i] + bv;
      }
    }
  }
}

// ---------------- aggregation: out = relu?(inv_cnt * sum_nb(yl) + yr) ----------------
template <int RELU>
__global__ __launch_bounds__(256) void agg_kernel(
    const float* __restrict__ yl, const float* __restrict__ yr,
    const int* __restrict__ row_ptr, const int* __restrict__ colv,
    const float* __restrict__ inv_cnt, float* __restrict__ out, int n) {
  int node = blockIdx.x * 4 + (threadIdx.x >> 6);
  if (node >= n) return;
  int lane = threadIdx.x & 63;
  int beg = row_ptr[node], end = row_ptr[node + 1];
  float ax = 0.f, ay = 0.f;
  int e = beg;
  for (; e + 4 <= end; e += 4) {
    int s0 = colv[e], s1 = colv[e + 1], s2 = colv[e + 2], s3 = colv[e + 3];
    float2 v0 = *(const float2*)(yl + (size_t)s0 * 128 + lane * 2);
    float2 v1 = *(const float2*)(yl + (size_t)s1 * 128 + lane * 2);
    float2 v2 = *(const float2*)(yl + (size_t)s2 * 128 + lane * 2);
    float2 v3 = *(const float2*)(yl + (size_t)s3 * 128 + lane * 2);
    ax += (v0.x + v1.x) + (v2.x + v3.x);
    ay += (v0.y + v1.y) + (v2.y + v3.y);
  }
  for (; e < end; ++e) {
    float2 v = *(const float2*)(yl + (size_t)colv[e] * 128 + lane * 2);
    ax += v.x;
    ay += v.y;
  }
  float s = inv_cnt[node];
  float2 r = *(const float2*)(yr + (size_t)node * 128 + lane * 2);
  float ox = ax * s + r.x;
  float oy = ay * s + r.y;
  if (RELU) {
    ox = fmaxf(ox, 0.f);
    oy = fmaxf(oy, 0.f);
  }
  float2 o = {ox, oy};
  *(float2*)(out + (size_t)node * 128 + lane * 2) = o;
}

// ---------------- launch ----------------
extern "C" void kernel_launch(void* const* d_in, const int* in_sizes, int n_in,
                              void* d_out, int out_size, void* d_ws, size_t ws_size,
                              hipStream_t stream) {
  const float* x = (const float*)d_in[0];
  const int* ei = (const int*)d_in[1];
  const float* Wl1 = (const float*)d_in[2];
  const float* Wr1 = (const float*)d_in[3];
  const float* b1 = (const float*)d_in[4];
  const float* Wl2 = (const float*)d_in[5];
  const float* Wr2 = (const float*)d_in[6];
  const float* b2 = (const float*)d_in[7];

  const int N = in_sizes[0] / 128;
  const int E = in_sizes[1] / 2;
  const int* srcv = ei;
  const int* dstv = ei + E;

  char* ws = (char*)d_ws;
  float* bufA = (float*)ws;   ws += (size_t)N * 128 * 4;   // xl / yl
  float* bufB = (float*)ws;   ws += (size_t)N * 128 * 4;   // xr / yr
  u16* G1 = (u16*)ws;         ws += 256 * 128 * 2;
  u16* G2 = (u16*)ws;         ws += 256 * 128 * 2;
  int* colv = (int*)ws;       ws += (size_t)E * 4;
  int* row_ptr = (int*)ws;    ws += ((size_t)N + 64) * 4;
  int* fill_pos = (int*)ws;   ws += (size_t)N * 4;
  int* cnt = (int*)ws;        ws += (size_t)N * 4;
  float* invc = (float*)ws;   ws += (size_t)N * 4;
  int* bsum = (int*)ws;       ws += 256 * 4;
  float* h = (float*)d_out;   // layer-1 output lives in d_out, overwritten by layer 2

  const int nsb = (N + SCAN_CHUNK - 1) / SCAN_CHUNK;

  hipMemsetAsync(cnt, 0, (size_t)N * 4, stream);
  prep_weights_kernel<<<128, 256, 0, stream>>>(Wl1, Wr1, G1);
  prep_weights_kernel<<<128, 256, 0, stream>>>(Wl2, Wr2, G2);
  hist_kernel<<<(E + 255) / 256, 256, 0, stream>>>(dstv, cnt, E);
  scan_sums<<<nsb, 256, 0, stream>>>(cnt, bsum, N);
  scan_bsum<<<1, 64, 0, stream>>>(bsum, nsb, row_ptr + N);
  scan_apply<<<nsb, 256, 0, stream>>>(cnt, bsum, row_ptr, fill_pos, invc, N);
  fill_kernel<<<(E + 255) / 256, 256, 0, stream>>>(srcv, dstv, fill_pos, colv, E);

  int gblocks = (N + 63) / 64;
  gemm_dual_kernel<<<gblocks, 256, 0, stream>>>(x, G1, b1, bufA, bufB, N);
  agg_kernel<1><<<(N + 3) / 4, 256, 0, stream>>>(bufA, bufB, row_ptr, colv, invc, h, N);
  gemm_dual_kernel<<<gblocks, 256, 0, stream>>>(h, G2, b2, bufA, bufB, N);
  agg_kernel<0><<<(N + 3) / 4, 256, 0, stream>>>(bufA, bufB, row_ptr, colv, invc, (float*)d_out, N);
}

// Round 3
// 209.893 us; speedup vs baseline: 1.6877x; 1.1175x over previous
//
#include <hip/hip_runtime.h>

typedef unsigned int u32;
typedef unsigned short u16;
typedef __attribute__((ext_vector_type(8))) short bf16x8;
typedef __attribute__((ext_vector_type(4))) float f32x4;

// ---------------- helpers ----------------
__device__ __forceinline__ u32 f2bf(float f) {
  u32 x = __float_as_uint(f);
  return (x + 0x7fffu + ((x >> 16) & 1u)) >> 16;   // RNE to bf16 bits
}
__device__ __forceinline__ float bf2f(u16 u) {
  return __uint_as_float(((u32)u) << 16);
}

// ---------------- weight prep: bf16, transposed, pre-swizzled ----------------
// G layout (u16): G[c*128 + (k ^ ((c&7)<<3))] = bf16(W[k][c]), c in [0,256):
//   c<128 -> Wl col c ; c>=128 -> Wr col (c-128).
__global__ void prep_weights_kernel(const float* __restrict__ Wl,
                                    const float* __restrict__ Wr,
                                    u16* __restrict__ G) {
  int id = blockIdx.x * 256 + threadIdx.x;
  if (id >= 256 * 128) return;
  int c = id >> 7;
  int k = id & 127;
  const float* W = (c < 128) ? Wl : Wr;
  float v = W[k * 128 + (c & 127)];
  G[c * 128 + (k ^ ((c & 7) << 3))] = (u16)f2bf(v);
}

// ---------------- CSR build ----------------
__global__ void hist_kernel(const int* __restrict__ dst, int* __restrict__ cnt, int E) {
  int e = blockIdx.x * blockDim.x + threadIdx.x;
  if (e < E) atomicAdd(&cnt[dst[e]], 1);
}

#define SCAN_CHUNK 2048

__global__ __launch_bounds__(256) void scan_sums(const int* __restrict__ cnt,
                                                 int* __restrict__ bsum, int n) {
  __shared__ int red[256];
  int t = threadIdx.x;
  int base = blockIdx.x * SCAN_CHUNK + t * 8;
  int s = 0;
#pragma unroll
  for (int i = 0; i < 8; ++i) {
    int idx = base + i;
    if (idx < n) s += cnt[idx];
  }
  red[t] = s;
  __syncthreads();
  for (int off = 128; off > 0; off >>= 1) {
    if (t < off) red[t] += red[t + off];
    __syncthreads();
  }
  if (t == 0) bsum[blockIdx.x] = red[0];
}

__global__ void scan_bsum(int* __restrict__ bsum, int nb, int* __restrict__ row_ptr_n) {
  if (threadIdx.x == 0) {
    int run = 0;
    for (int i = 0; i < nb; ++i) {
      int c = bsum[i];
      bsum[i] = run;
      run += c;
    }
    *row_ptr_n = run;   // row_ptr[n] = E
  }
}

__global__ __launch_bounds__(256) void scan_apply(
    const int* __restrict__ cnt, const int* __restrict__ bsum,
    int* __restrict__ row_ptr, int* __restrict__ fill_pos,
    float* __restrict__ inv_cnt, int n) {
  __shared__ int sc[256];
  int t = threadIdx.x;
  int base = blockIdx.x * SCAN_CHUNK + t * 8;
  int v[8];
  int s = 0;
#pragma unroll
  for (int i = 0; i < 8; ++i) {
    int idx = base + i;
    v[i] = (idx < n) ? cnt[idx] : 0;
    s += v[i];
  }
  sc[t] = s;
  __syncthreads();
  for (int off = 1; off < 256; off <<= 1) {
    int add = (t >= off) ? sc[t - off] : 0;
    __syncthreads();
    sc[t] += add;
    __syncthreads();
  }
  int run = bsum[blockIdx.x] + ((t > 0) ? sc[t - 1] : 0);
#pragma unroll
  for (int i = 0; i < 8; ++i) {
    int idx = base + i;
    if (idx < n) {
      row_ptr[idx] = run;
      fill_pos[idx] = run;
      inv_cnt[idx] = 1.0f / (float)max(v[i], 1);
      run += v[i];
    }
  }
}

__global__ void fill_kernel(const int* __restrict__ src, const int* __restrict__ dst,
                            int* __restrict__ fill_pos, int* __restrict__ col, int E) {
  int e = blockIdx.x * blockDim.x + threadIdx.x;
  if (e < E) {
    int d = dst[e];
    int pos = atomicAdd(&fill_pos[d], 1);
    col[pos] = src[e];
  }
}

// ---------------- fused dual GEMM: yl(bf16) = in@Wl ; yr(f32) = in@Wr + b ------
// IN_BF16: 0 -> in is fp32 [n][128], 1 -> in is bf16 (u16) [n][128]
// 64 rows x 256 cols per block. LDS 80KB, XOR-swizzled tiles.
template <int IN_BF16>
__global__ __launch_bounds__(256, 2) void gemm_dual_kernel(
    const void* __restrict__ in_, const u16* __restrict__ G,
    const float* __restrict__ bias, u16* __restrict__ yl, float* __restrict__ yr, int n) {
  __shared__ uint4 lds4[5120];                 // 80 KB
  char* As = (char*)lds4;                      // bytes [0, 16384)
  char* Bt = (char*)lds4 + 16384;              // bytes [16384, 81920)
  const int t = threadIdx.x;
  const int lane = t & 63;
  const int wave = t >> 6;
  const int row0 = blockIdx.x * 64;

  // stage B: linear 64 KB copy (G is pre-swizzled)
  {
    const uint4* gb = (const uint4*)G;
    uint4* lb = lds4 + 1024;
#pragma unroll
    for (int i = 0; i < 16; ++i) lb[i * 256 + t] = gb[i * 256 + t];
  }
  // stage A: 64 rows x 128 elems -> bf16, swizzled 16B granules
#pragma unroll
  for (int i = 0; i < 4; ++i) {
    int g = t + i * 256;                       // granule id 0..1023
    int r = g >> 4;
    int gc = g & 15;
    int row = row0 + r;
    uint4 pk = {0u, 0u, 0u, 0u};
    if (row < n) {
      if (IN_BF16) {
        pk = *(const uint4*)((const u16*)in_ + (size_t)row * 128 + gc * 8);
      } else {
        const float4* p = (const float4*)((const float*)in_ + (size_t)row * 128 + gc * 8);
        float4 v0 = p[0], v1 = p[1];
        pk.x = f2bf(v0.x) | (f2bf(v0.y) << 16);
        pk.y = f2bf(v0.z) | (f2bf(v0.w) << 16);
        pk.z = f2bf(v1.x) | (f2bf(v1.y) << 16);
        pk.w = f2bf(v1.z) | (f2bf(v1.w) << 16);
      }
    }
    *(uint4*)(As + r * 256 + ((gc * 16) ^ ((r & 7) << 4))) = pk;
  }
  __syncthreads();

  const int wr = wave >> 1;                    // 0..1 : rows wr*32
  const int wc = wave & 1;                     // 0 -> yl cols, 1 -> yr cols
  const int lhi = lane >> 4;
  const int llo = lane & 15;

  f32x4 acc[2][8];
#pragma unroll
  for (int fr = 0; fr < 2; ++fr)
#pragma unroll
    for (int fc = 0; fc < 8; ++fc) acc[fr][fc] = {0.f, 0.f, 0.f, 0.f};

#pragma unroll
  for (int ks = 0; ks < 4; ++ks) {
    const int kbyte = ks * 64 + lhi * 16;
    bf16x8 a[2], b[8];
#pragma unroll
    for (int fr = 0; fr < 2; ++fr) {
      int r = wr * 32 + fr * 16 + llo;
      a[fr] = *(const bf16x8*)(As + r * 256 + (kbyte ^ ((r & 7) << 4)));
    }
#pragma unroll
    for (int fc = 0; fc < 8; ++fc) {
      int c = wc * 128 + fc * 16 + llo;
      b[fc] = *(const bf16x8*)(Bt + c * 256 + (kbyte ^ ((c & 7) << 4)));
    }
#pragma unroll
    for (int fr = 0; fr < 2; ++fr)
#pragma unroll
      for (int fc = 0; fc < 8; ++fc)
        acc[fr][fc] = __builtin_amdgcn_mfma_f32_16x16x32_bf16(a[fr], b[fc], acc[fr][fc], 0, 0, 0);
  }

  // epilogue: C layout col=lane&15, row=(lane>>4)*4+i  (m89-verified)
  if (wc == 0) {
    // yl: bf16 out, no bias
#pragma unroll
    for (int fc = 0; fc < 8; ++fc) {
      int cc = fc * 16 + llo;
#pragma unroll
      for (int fr = 0; fr < 2; ++fr) {
#pragma unroll
        for (int i = 0; i < 4; ++i) {
          int row = row0 + wr * 32 + fr * 16 + lhi * 4 + i;
          if (row < n) yl[(size_t)row * 128 + cc] = (u16)f2bf(acc[fr][fc][i]);
        }
      }
    }
  } else {
    // yr: fp32 out + bias
#pragma unroll
    for (int fc = 0; fc < 8; ++fc) {
      int cc = fc * 16 + llo;
      float bv = bias[cc];
#pragma unroll
      for (int fr = 0; fr < 2; ++fr) {
#pragma unroll
        for (int i = 0; i < 4; ++i) {
          int row = row0 + wr * 32 + fr * 16 + lhi * 4 + i;
          if (row < n) yr[(size_t)row * 128 + cc] = acc[fr][fc][i] + bv;
        }
      }
    }
  }
}

// ------- aggregation: out = relu?(inv_cnt * sum_nb(yl_bf16) + yr_f32) ----------
// OUT_BF16: 1 -> out is u16 bf16 [n][128], 0 -> fp32
template <int RELU, int OUT_BF16>
__global__ __launch_bounds__(256) void agg_kernel(
    const u16* __restrict__ yl, const float* __restrict__ yr,
    const int* __restrict__ row_ptr, const int* __restrict__ colv,
    const float* __restrict__ inv_cnt, void* __restrict__ out_, int n) {
  int node = blockIdx.x * 4 + (threadIdx.x >> 6);
  if (node >= n) return;
  int lane = threadIdx.x & 63;
  int beg = row_ptr[node], end = row_ptr[node + 1];
  float ax = 0.f, ay = 0.f;
  int e = beg;
  for (; e + 4 <= end; e += 4) {
    int s0 = colv[e], s1 = colv[e + 1], s2 = colv[e + 2], s3 = colv[e + 3];
    ushort2 v0 = *(const ushort2*)(yl + (size_t)s0 * 128 + lane * 2);
    ushort2 v1 = *(const ushort2*)(yl + (size_t)s1 * 128 + lane * 2);
    ushort2 v2 = *(const ushort2*)(yl + (size_t)s2 * 128 + lane * 2);
    ushort2 v3 = *(const ushort2*)(yl + (size_t)s3 * 128 + lane * 2);
    ax += (bf2f(v0.x) + bf2f(v1.x)) + (bf2f(v2.x) + bf2f(v3.x));
    ay += (bf2f(v0.y) + bf2f(v1.y)) + (bf2f(v2.y) + bf2f(v3.y));
  }
  for (; e < end; ++e) {
    ushort2 v = *(const ushort2*)(yl + (size_t)colv[e] * 128 + lane * 2);
    ax += bf2f(v.x);
    ay += bf2f(v.y);
  }
  float s = inv_cnt[node];
  float2 r = *(const float2*)(yr + (size_t)node * 128 + lane * 2);
  float ox = ax * s + r.x;
  float oy = ay * s + r.y;
  if (RELU) {
    ox = fmaxf(ox, 0.f);
    oy = fmaxf(oy, 0.f);
  }
  if (OUT_BF16) {
    ushort2 o = {(u16)f2bf(ox), (u16)f2bf(oy)};
    *(ushort2*)((u16*)out_ + (size_t)node * 128 + lane * 2) = o;
  } else {
    float2 o = {ox, oy};
    *(float2*)((float*)out_ + (size_t)node * 128 + lane * 2) = o;
  }
}

// ---------------- launch ----------------
extern "C" void kernel_launch(void* const* d_in, const int* in_sizes, int n_in,
                              void* d_out, int out_size, void* d_ws, size_t ws_size,
                              hipStream_t stream) {
  const float* x = (const float*)d_in[0];
  const int* ei = (const int*)d_in[1];
  const float* Wl1 = (const float*)d_in[2];
  const float* Wr1 = (const float*)d_in[3];
  const float* b1 = (const float*)d_in[4];
  const float* Wl2 = (const float*)d_in[5];
  const float* Wr2 = (const float*)d_in[6];
  const float* b2 = (const float*)d_in[7];

  const int N = in_sizes[0] / 128;
  const int E = in_sizes[1] / 2;
  const int* srcv = ei;
  const int* dstv = ei + E;

  char* ws = (char*)d_ws;
  u16* yl = (u16*)ws;         ws += (size_t)N * 128 * 2;   // GEMM left output (bf16)
  float* yr = (float*)ws;     ws += (size_t)N * 128 * 4;   // GEMM right output (fp32)
  u16* hbf = (u16*)ws;        ws += (size_t)N * 128 * 2;   // layer-1 activations (bf16)
  u16* G1 = (u16*)ws;         ws += 256 * 128 * 2;
  u16* G2 = (u16*)ws;         ws += 256 * 128 * 2;
  int* colv = (int*)ws;       ws += (size_t)E * 4;
  int* row_ptr = (int*)ws;    ws += ((size_t)N + 64) * 4;
  int* fill_pos = (int*)ws;   ws += (size_t)N * 4;
  int* cnt = (int*)ws;        ws += (size_t)N * 4;
  float* invc = (float*)ws;   ws += (size_t)N * 4;
  int* bsum = (int*)ws;       ws += 256 * 4;

  const int nsb = (N + SCAN_CHUNK - 1) / SCAN_CHUNK;

  hipMemsetAsync(cnt, 0, (size_t)N * 4, stream);
  prep_weights_kernel<<<128, 256, 0, stream>>>(Wl1, Wr1, G1);
  prep_weights_kernel<<<128, 256, 0, stream>>>(Wl2, Wr2, G2);
  hist_kernel<<<(E + 255) / 256, 256, 0, stream>>>(dstv, cnt, E);
  scan_sums<<<nsb, 256, 0, stream>>>(cnt, bsum, N);
  scan_bsum<<<1, 64, 0, stream>>>(bsum, nsb, row_ptr + N);
  scan_apply<<<nsb, 256, 0, stream>>>(cnt, bsum, row_ptr, fill_pos, invc, N);
  fill_kernel<<<(E + 255) / 256, 256, 0, stream>>>(srcv, dstv, fill_pos, colv, E);

  int gblocks = (N + 63) / 64;
  gemm_dual_kernel<0><<<gblocks, 256, 0, stream>>>(x, G1, b1, yl, yr, N);
  agg_kernel<1, 1><<<(N + 3) / 4, 256, 0, stream>>>(yl, yr, row_ptr, colv, invc, hbf, N);
  gemm_dual_kernel<1><<<gblocks, 256, 0, stream>>>(hbf, G2, b2, yl, yr, N);
  agg_kernel<0, 0><<<(N + 3) / 4, 256, 0, stream>>>(yl, yr, row_ptr, colv, invc, d_out, N);
}

// Round 4
// 189.960 us; speedup vs baseline: 1.8648x; 1.1049x over previous
//
#include <hip/hip_runtime.h>

typedef unsigned int u32;
typedef unsigned short u16;
typedef __attribute__((ext_vector_type(8))) short bf16x8;
typedef __attribute__((ext_vector_type(4))) float f32x4;

// ---------------- helpers ----------------
__device__ __forceinline__ u32 f2bf(float f) {
  u32 x = __float_as_uint(f);
  return (x + 0x7fffu + ((x >> 16) & 1u)) >> 16;   // RNE to bf16 bits
}
__device__ __forceinline__ float bf2f(u16 u) {
  return __uint_as_float(((u32)u) << 16);
}
__device__ __forceinline__ void addbf8(float* a, uint4 v) {
  a[0] += bf2f((u16)v.x); a[1] += bf2f((u16)(v.x >> 16));
  a[2] += bf2f((u16)v.y); a[3] += bf2f((u16)(v.y >> 16));
  a[4] += bf2f((u16)v.z); a[5] += bf2f((u16)(v.z >> 16));
  a[6] += bf2f((u16)v.w); a[7] += bf2f((u16)(v.w >> 16));
}

// ---------------- setup: zero cnt + prep both weight buffers ----------------
// G layout (u16): G[c*128 + (k ^ ((c&7)<<3))] = bf16(W[k][c]), c in [0,256):
//   c<128 -> Wl col c ; c>=128 -> Wr col (c-128). Linear LDS copy -> swizzled tile.
__global__ void setup_kernel(const float* __restrict__ Wl1, const float* __restrict__ Wr1,
                             const float* __restrict__ Wl2, const float* __restrict__ Wr2,
                             u16* __restrict__ G1, u16* __restrict__ G2,
                             int* __restrict__ cnt, int n) {
  int b = blockIdx.x;
  if (b < 256) {
    const float* Wl = (b < 128) ? Wl1 : Wl2;
    const float* Wr = (b < 128) ? Wr1 : Wr2;
    u16* G = (b < 128) ? G1 : G2;
    int id = (b & 127) * 256 + threadIdx.x;       // 0..32767
    int c = id >> 7;
    int k = id & 127;
    const float* W = (c < 128) ? Wl : Wr;
    float v = W[k * 128 + (c & 127)];
    G[c * 128 + (k ^ ((c & 7) << 3))] = (u16)f2bf(v);
  } else {
    int i = (b - 256) * 256 + threadIdx.x;
    if (i < n) cnt[i] = 0;
  }
}

// ---------------- CSR build ----------------
__global__ void hist_kernel(const int* __restrict__ dst, int* __restrict__ cnt, int E) {
  int e = blockIdx.x * blockDim.x + threadIdx.x;
  if (e < E) atomicAdd(&cnt[dst[e]], 1);
}

#define SCAN_CHUNK 2048

__global__ __launch_bounds__(256) void scan_sums(const int* __restrict__ cnt,
                                                 int* __restrict__ bsum, int n) {
  __shared__ int red[256];
  int t = threadIdx.x;
  int base = blockIdx.x * SCAN_CHUNK + t * 8;
  int s = 0;
#pragma unroll
  for (int i = 0; i < 8; ++i) {
    int idx = base + i;
    if (idx < n) s += cnt[idx];
  }
  red[t] = s;
  __syncthreads();
  for (int off = 128; off > 0; off >>= 1) {
    if (t < off) red[t] += red[t + off];
    __syncthreads();
  }
  if (t == 0) bsum[blockIdx.x] = red[0];
}

__global__ void scan_bsum(int* __restrict__ bsum, int nb, int* __restrict__ row_ptr_n) {
  if (threadIdx.x == 0) {
    int run = 0;
    for (int i = 0; i < nb; ++i) {
      int c = bsum[i];
      bsum[i] = run;
      run += c;
    }
    *row_ptr_n = run;   // row_ptr[n] = E
  }
}

__global__ __launch_bounds__(256) void scan_apply(
    const int* __restrict__ cnt, const int* __restrict__ bsum,
    int* __restrict__ row_ptr, int* __restrict__ fill_pos,
    float* __restrict__ inv_cnt, int n) {
  __shared__ int sc[256];
  int t = threadIdx.x;
  int base = blockIdx.x * SCAN_CHUNK + t * 8;
  int v[8];
  int s = 0;
#pragma unroll
  for (int i = 0; i < 8; ++i) {
    int idx = base + i;
    v[i] = (idx < n) ? cnt[idx] : 0;
    s += v[i];
  }
  sc[t] = s;
  __syncthreads();
  for (int off = 1; off < 256; off <<= 1) {
    int add = (t >= off) ? sc[t - off] : 0;
    __syncthreads();
    sc[t] += add;
    __syncthreads();
  }
  int run = bsum[blockIdx.x] + ((t > 0) ? sc[t - 1] : 0);
#pragma unroll
  for (int i = 0; i < 8; ++i) {
    int idx = base + i;
    if (idx < n) {
      row_ptr[idx] = run;
      fill_pos[idx] = run;
      inv_cnt[idx] = 1.0f / (float)max(v[i], 1);
      run += v[i];
    }
  }
}

__global__ void fill_kernel(const int* __restrict__ src, const int* __restrict__ dst,
                            int* __restrict__ fill_pos, int* __restrict__ col, int E) {
  int e = blockIdx.x * blockDim.x + threadIdx.x;
  if (e < E) {
    int d = dst[e];
    int pos = atomicAdd(&fill_pos[d], 1);
    col[pos] = src[e];
  }
}

// ------ fused dual GEMM: yl(bf16) = in@Wl ; yr(bf16) = in@Wr + b ------
// IN_BF16: 0 -> in fp32 [n][128], 1 -> in bf16 [n][128]
// 64 rows x 256 cols per block. LDS 80KB, XOR-swizzled tiles.
template <int IN_BF16>
__global__ __launch_bounds__(256, 2) void gemm_dual_kernel(
    const void* __restrict__ in_, const u16* __restrict__ G,
    const float* __restrict__ bias, u16* __restrict__ yl, u16* __restrict__ yr, int n) {
  __shared__ uint4 lds4[5120];                 // 80 KB
  char* As = (char*)lds4;                      // bytes [0, 16384)
  char* Bt = (char*)lds4 + 16384;              // bytes [16384, 81920)
  const int t = threadIdx.x;
  const int lane = t & 63;
  const int wave = t >> 6;
  const int row0 = blockIdx.x * 64;

  // stage B: linear 64 KB copy (G is pre-swizzled)
  {
    const uint4* gb = (const uint4*)G;
    uint4* lb = lds4 + 1024;
#pragma unroll
    for (int i = 0; i < 16; ++i) lb[i * 256 + t] = gb[i * 256 + t];
  }
  // stage A: 64 rows x 128 elems -> bf16, swizzled 16B granules
#pragma unroll
  for (int i = 0; i < 4; ++i) {
    int g = t + i * 256;                       // granule id 0..1023
    int r = g >> 4;
    int gc = g & 15;
    int row = row0 + r;
    uint4 pk = {0u, 0u, 0u, 0u};
    if (row < n) {
      if (IN_BF16) {
        pk = *(const uint4*)((const u16*)in_ + (size_t)row * 128 + gc * 8);
      } else {
        const float4* p = (const float4*)((const float*)in_ + (size_t)row * 128 + gc * 8);
        float4 v0 = p[0], v1 = p[1];
        pk.x = f2bf(v0.x) | (f2bf(v0.y) << 16);
        pk.y = f2bf(v0.z) | (f2bf(v0.w) << 16);
        pk.z = f2bf(v1.x) | (f2bf(v1.y) << 16);
        pk.w = f2bf(v1.z) | (f2bf(v1.w) << 16);
      }
    }
    *(uint4*)(As + r * 256 + ((gc * 16) ^ ((r & 7) << 4))) = pk;
  }
  __syncthreads();

  const int wr = wave >> 1;                    // 0..1 : rows wr*32
  const int wc = wave & 1;                     // 0 -> yl cols, 1 -> yr cols
  const int lhi = lane >> 4;
  const int llo = lane & 15;

  f32x4 acc[2][8];
#pragma unroll
  for (int fr = 0; fr < 2; ++fr)
#pragma unroll
    for (int fc = 0; fc < 8; ++fc) acc[fr][fc] = {0.f, 0.f, 0.f, 0.f};

#pragma unroll
  for (int ks = 0; ks < 4; ++ks) {
    const int kbyte = ks * 64 + lhi * 16;
    bf16x8 a[2], b[8];
#pragma unroll
    for (int fr = 0; fr < 2; ++fr) {
      int r = wr * 32 + fr * 16 + llo;
      a[fr] = *(const bf16x8*)(As + r * 256 + (kbyte ^ ((r & 7) << 4)));
    }
#pragma unroll
    for (int fc = 0; fc < 8; ++fc) {
      int c = wc * 128 + fc * 16 + llo;
      b[fc] = *(const bf16x8*)(Bt + c * 256 + (kbyte ^ ((c & 7) << 4)));
    }
#pragma unroll
    for (int fr = 0; fr < 2; ++fr)
#pragma unroll
      for (int fc = 0; fc < 8; ++fc)
        acc[fr][fc] = __builtin_amdgcn_mfma_f32_16x16x32_bf16(a[fr], b[fc], acc[fr][fc], 0, 0, 0);
  }

  // epilogue: C layout col=lane&15, row=(lane>>4)*4+i  (m89-verified)
  if (wc == 0) {
#pragma unroll
    for (int fc = 0; fc < 8; ++fc) {
      int cc = fc * 16 + llo;
#pragma unroll
      for (int fr = 0; fr < 2; ++fr) {
#pragma unroll
        for (int i = 0; i < 4; ++i) {
          int row = row0 + wr * 32 + fr * 16 + lhi * 4 + i;
          if (row < n) yl[(size_t)row * 128 + cc] = (u16)f2bf(acc[fr][fc][i]);
        }
      }
    }
  } else {
#pragma unroll
    for (int fc = 0; fc < 8; ++fc) {
      int cc = fc * 16 + llo;
      float bv = bias[cc];
#pragma unroll
      for (int fr = 0; fr < 2; ++fr) {
#pragma unroll
        for (int i = 0; i < 4; ++i) {
          int row = row0 + wr * 32 + fr * 16 + lhi * 4 + i;
          if (row < n) yr[(size_t)row * 128 + cc] = (u16)f2bf(acc[fr][fc][i] + bv);
        }
      }
    }
  }
}

// ------- aggregation: out = relu?(inv_cnt * sum_nb(yl) + yr), all bf16 in -------
// One node per 16-lane group (uint4 = 8 bf16/lane), 16 nodes/block, 4-row unroll.
// OUT_BF16: 1 -> out u16 [n][128], 0 -> fp32 [n][128]
template <int RELU, int OUT_BF16>
__global__ __launch_bounds__(256) void agg_kernel(
    const u16* __restrict__ yl, const u16* __restrict__ yr,
    const int* __restrict__ row_ptr, const int* __restrict__ colv,
    const float* __restrict__ inv_cnt, void* __restrict__ out_, int n) {
  int node = blockIdx.x * 16 + (threadIdx.x >> 4);
  if (node >= n) return;
  int sl = threadIdx.x & 15;
  int beg = row_ptr[node], end = row_ptr[node + 1];
  float a[8] = {0.f, 0.f, 0.f, 0.f, 0.f, 0.f, 0.f, 0.f};
  int e = beg;
  for (; e + 4 <= end; e += 4) {
    int s0 = colv[e], s1 = colv[e + 1], s2 = colv[e + 2], s3 = colv[e + 3];
    uint4 v0 = *(const uint4*)(yl + (size_t)s0 * 128 + sl * 8);
    uint4 v1 = *(const uint4*)(yl + (size_t)s1 * 128 + sl * 8);
    uint4 v2 = *(const uint4*)(yl + (size_t)s2 * 128 + sl * 8);
    uint4 v3 = *(const uint4*)(yl + (size_t)s3 * 128 + sl * 8);
    addbf8(a, v0); addbf8(a, v1); addbf8(a, v2); addbf8(a, v3);
  }
  for (; e < end; ++e) {
    uint4 v = *(const uint4*)(yl + (size_t)colv[e] * 128 + sl * 8);
    addbf8(a, v);
  }
  float s = inv_cnt[node];
  uint4 rv = *(const uint4*)(yr + (size_t)node * 128 + sl * 8);
  float r[8];
  r[0] = bf2f((u16)rv.x); r[1] = bf2f((u16)(rv.x >> 16));
  r[2] = bf2f((u16)rv.y); r[3] = bf2f((u16)(rv.y >> 16));
  r[4] = bf2f((u16)rv.z); r[5] = bf2f((u16)(rv.z >> 16));
  r[6] = bf2f((u16)rv.w); r[7] = bf2f((u16)(rv.w >> 16));
  float o[8];
#pragma unroll
  for (int j = 0; j < 8; ++j) {
    o[j] = a[j] * s + r[j];
    if (RELU) o[j] = fmaxf(o[j], 0.f);
  }
  if (OUT_BF16) {
    uint4 p;
    p.x = f2bf(o[0]) | (f2bf(o[1]) << 16);
    p.y = f2bf(o[2]) | (f2bf(o[3]) << 16);
    p.z = f2bf(o[4]) | (f2bf(o[5]) << 16);
    p.w = f2bf(o[6]) | (f2bf(o[7]) << 16);
    *(uint4*)((u16*)out_ + (size_t)node * 128 + sl * 8) = p;
  } else {
    float4 q0 = {o[0], o[1], o[2], o[3]};
    float4 q1 = {o[4], o[5], o[6], o[7]};
    float* op = (float*)out_ + (size_t)node * 128 + sl * 8;
    *(float4*)op = q0;
    *(float4*)(op + 4) = q1;
  }
}

// ---------------- launch ----------------
extern "C" void kernel_launch(void* const* d_in, const int* in_sizes, int n_in,
                              void* d_out, int out_size, void* d_ws, size_t ws_size,
                              hipStream_t stream) {
  const float* x = (const float*)d_in[0];
  const int* ei = (const int*)d_in[1];
  const float* Wl1 = (const float*)d_in[2];
  const float* Wr1 = (const float*)d_in[3];
  const float* b1 = (const float*)d_in[4];
  const float* Wl2 = (const float*)d_in[5];
  const float* Wr2 = (const float*)d_in[6];
  const float* b2 = (const float*)d_in[7];

  const int N = in_sizes[0] / 128;
  const int E = in_sizes[1] / 2;
  const int* srcv = ei;
  const int* dstv = ei + E;

  char* ws = (char*)d_ws;
  u16* yl = (u16*)ws;         ws += (size_t)N * 128 * 2;   // GEMM left output (bf16)
  u16* yr = (u16*)ws;         ws += (size_t)N * 128 * 2;   // GEMM right output (bf16)
  u16* hbf = (u16*)ws;        ws += (size_t)N * 128 * 2;   // layer-1 activations (bf16)
  u16* G1 = (u16*)ws;         ws += 256 * 128 * 2;
  u16* G2 = (u16*)ws;         ws += 256 * 128 * 2;
  int* colv = (int*)ws;       ws += (size_t)E * 4;
  int* row_ptr = (int*)ws;    ws += ((size_t)N + 64) * 4;
  int* fill_pos = (int*)ws;   ws += (size_t)N * 4;
  int* cnt = (int*)ws;        ws += (size_t)N * 4;
  float* invc = (float*)ws;   ws += (size_t)N * 4;
  int* bsum = (int*)ws;       ws += 256 * 4;

  const int nsb = (N + SCAN_CHUNK - 1) / SCAN_CHUNK;

  setup_kernel<<<256 + (N + 255) / 256, 256, 0, stream>>>(Wl1, Wr1, Wl2, Wr2, G1, G2, cnt, N);
  hist_kernel<<<(E + 255) / 256, 256, 0, stream>>>(dstv, cnt, E);
  scan_sums<<<nsb, 256, 0, stream>>>(cnt, bsum, N);
  scan_bsum<<<1, 64, 0, stream>>>(bsum, nsb, row_ptr + N);
  scan_apply<<<nsb, 256, 0, stream>>>(cnt, bsum, row_ptr, fill_pos, invc, N);
  fill_kernel<<<(E + 255) / 256, 256, 0, stream>>>(srcv, dstv, fill_pos, colv, E);

  int gblocks = (N + 63) / 64;
  gemm_dual_kernel<0><<<gblocks, 256, 0, stream>>>(x, G1, b1, yl, yr, N);
  agg_kernel<1, 1><<<(N + 15) / 16, 256, 0, stream>>>(yl, yr, row_ptr, colv, invc, hbf, N);
  gemm_dual_kernel<1><<<gblocks, 256, 0, stream>>>(hbf, G2, b2, yl, yr, N);
  agg_kernel<0, 0><<<(N + 15) / 16, 256, 0, stream>>>(yl, yr, row_ptr, colv, invc, d_out, N);
}